// Round 2
// 1116.536 us; speedup vs baseline: 1.1570x; 1.1570x over previous
//
#include <hip/hip_runtime.h>

#define TOK   8192
#define HD    1024
#define NI    2816
#define NI2   5632
#define NEXP  8
#define MAXROWS 17408   // 16384 + 8*128 worst-case padding

typedef __attribute__((ext_vector_type(8))) short short8;
typedef __attribute__((ext_vector_type(4))) float f32x4;

// ---------- helpers ----------
__device__ __forceinline__ float bf2f(short v) {
    union { unsigned u; float f; } c; c.u = ((unsigned)(unsigned short)v) << 16; return c.f;
}
__device__ __forceinline__ short f2bf(float f) {
    union { float f; unsigned u; } c; c.f = f;
    unsigned r = c.u + 0x7fff + ((c.u >> 16) & 1);   // RNE
    return (short)(r >> 16);
}
// async global->LDS, 16B per lane. LDS dest = wave-uniform base + lane*16.
__device__ __forceinline__ void gload16(const short* g, short* l) {
    __builtin_amdgcn_global_load_lds(
        (const __attribute__((address_space(1))) void*)(g),
        (__attribute__((address_space(3))) void*)(l),
        16, 0, 0);
}

// ---------- 0. dtype detect: fp32 read as bf16 has huge exponents ----------
__global__ void detect_kernel(const unsigned short* __restrict__ xs, int* __restrict__ ctrl)
{
    int bad = 0;
    for (int i = threadIdx.x; i < 4096; i += 256) {
        int e = (xs[i] >> 7) & 0xFF;
        if (e >= 137) bad = 1;
    }
    if (bad) atomicOr(&ctrl[31], 1);          // flag=1 -> inputs are fp32
}

// ---------- 0b. x -> bf16 (convert or copy) ----------
__global__ __launch_bounds__(256) void cvt_x_kernel(
    const void* __restrict__ xraw, short* __restrict__ xbf, const int* __restrict__ ctrl)
{
    int i = blockIdx.x * 256 + threadIdx.x;
    int flag = ctrl[31];
    xbf[i] = flag ? f2bf(((const float*)xraw)[i]) : ((const short*)xraw)[i];
}

// ---------- 0c. weight convert + TRANSPOSE: src [E][rows][cols] -> dst [E][cols][rows] bf16 ----------
__global__ __launch_bounds__(256) void transpose_w_kernel(
    const void* __restrict__ src, short* __restrict__ dst,
    const int* __restrict__ ctrl, int rows, int cols)
{
    const int flag = ctrl[31];
    __shared__ short tile[64][72];
    const long ebase = (long)blockIdx.z * rows * cols;
    const int r0 = blockIdx.y * 64, c0 = blockIdx.x * 64;
    const int lr = threadIdx.x >> 2, lc = (threadIdx.x & 3) * 16;

    if (flag) {
        const float* s = (const float*)src + ebase + (long)(r0 + lr) * cols + c0 + lc;
#pragma unroll
        for (int j = 0; j < 16; j += 4) {
            f32x4 v = *(const f32x4*)(s + j);
            tile[lr][lc + j + 0] = f2bf(v.x);
            tile[lr][lc + j + 1] = f2bf(v.y);
            tile[lr][lc + j + 2] = f2bf(v.z);
            tile[lr][lc + j + 3] = f2bf(v.w);
        }
    } else {
        const short* s = (const short*)src + ebase + (long)(r0 + lr) * cols + c0 + lc;
#pragma unroll
        for (int j = 0; j < 16; j += 8)
            *(short8*)&tile[lr][lc + j] = *(const short8*)(s + j);
    }
    __syncthreads();
    short* d = dst + ebase + (long)(c0 + lr) * rows + r0 + lc;
    short8 o0, o1;
#pragma unroll
    for (int j = 0; j < 8; j++) o0[j] = tile[lc + j][lr];
#pragma unroll
    for (int j = 0; j < 8; j++) o1[j] = tile[lc + 8 + j][lr];
    *(short8*)(d) = o0;
    *(short8*)(d + 8) = o1;
}

// ---------- 1. gating: logits -> top2 -> renorm ----------
__global__ __launch_bounds__(256) void gate_kernel(
    const void* __restrict__ xraw, const void* __restrict__ gwraw,
    int* __restrict__ top_i, float* __restrict__ top_w, int* __restrict__ ctrl)
{
    const int flag = ctrl[31];
    const float* xf = (const float*)xraw;  const short* xs = (const short*)xraw;
    const float* gf = (const float*)gwraw; const short* gs = (const short*)gwraw;
    const int wave = threadIdx.x >> 6, lane = threadIdx.x & 63;
    const int t = blockIdx.x * 4 + wave;
    float acc[NEXP] = {0.f, 0.f, 0.f, 0.f, 0.f, 0.f, 0.f, 0.f};
    for (int i = lane; i < HD; i += 64) {
        float xv = flag ? xf[t * HD + i] : bf2f(xs[t * HD + i]);
#pragma unroll
        for (int e = 0; e < NEXP; e++) {
            float wv = flag ? gf[e * HD + i] : bf2f(gs[e * HD + i]);
            acc[e] += xv * wv;
        }
    }
#pragma unroll
    for (int e = 0; e < NEXP; e++)
        for (int off = 32; off > 0; off >>= 1) acc[e] += __shfl_down(acc[e], off, 64);
    if (lane == 0) {
        int a = 0; float va = acc[0];
#pragma unroll
        for (int e = 1; e < NEXP; e++) if (acc[e] > va) { a = e; va = acc[e]; }
        int b = -1; float vb = -1e30f;
#pragma unroll
        for (int e = 0; e < NEXP; e++) if (e != a && acc[e] > vb) { b = e; vb = acc[e]; }
        float r = __expf(vb - va);
        float wa = 1.f / (1.f + r), wb = r / (1.f + r);
        top_i[2 * t] = a;     top_w[2 * t] = wa;
        top_i[2 * t + 1] = b; top_w[2 * t + 1] = wb;
        atomicAdd(&ctrl[a], 1);
        atomicAdd(&ctrl[b], 1);
    }
}

// ---------- 2. offsets (padded to 128) + pad dummy rows ----------
__global__ void offsets_pad_kernel(int* __restrict__ ctrl,
                                   int* __restrict__ rows_tok, float* __restrict__ rows_w)
{
    __shared__ int soff[NEXP + 1];
    if (threadIdx.x == 0) {
        int off = 0;
        for (int e = 0; e < NEXP; e++) {
            soff[e] = off; ctrl[16 + e] = off;
            off += (ctrl[e] + 127) & ~127;
        }
        soff[NEXP] = off; ctrl[24] = off;
    }
    __syncthreads();
    for (int e = 0; e < NEXP; e++) {
        int c = ctrl[e];
        int start = soff[e], len = soff[e + 1] - soff[e];
        for (int s = c + (int)threadIdx.x; s < len; s += blockDim.x) {
            rows_tok[start + s] = 0;
            rows_w[start + s] = 0.f;
        }
    }
}

// ---------- 3. scatter tokens into expert row lists ----------
__global__ __launch_bounds__(256) void scatter_kernel(
    const int* __restrict__ top_i, const float* __restrict__ top_w,
    int* __restrict__ ctrl, int* __restrict__ rows_tok, float* __restrict__ rows_w)
{
    int t = blockIdx.x * 256 + threadIdx.x;
    if (t >= TOK) return;
#pragma unroll
    for (int k = 0; k < 2; k++) {
        int e = top_i[2 * t + k];
        int pos = atomicAdd(&ctrl[8 + e], 1);
        int row = ctrl[16 + e] + pos;
        rows_tok[row] = t;
        rows_w[row] = top_w[2 * t + k];
    }
}

// ---------- 4. GEMM1: act = silu(x@Wg) * (x@Wu) ----------
// m97 structure: 128 rows x 64 act-cols (gate+up), BK=32, global_load_lds staging,
// XOR-swizzled linear LDS (swizzle applied on the per-lane GLOBAL source + the frag read).
__global__ __launch_bounds__(256) void gemm1_kernel(
    const short* __restrict__ xbf, const short* __restrict__ w1T,
    const int* __restrict__ rows_tok, const int* __restrict__ ctrl,
    short* __restrict__ act, int r0base)
{
    const int row0 = r0base + blockIdx.y * 128;
    if (row0 >= ctrl[24]) return;
    int e = 0;
#pragma unroll
    for (int q = 1; q < NEXP; q++) if (row0 >= ctrl[16 + q]) e = q;
    const int i0 = blockIdx.x * 64;

    __shared__ __align__(16) short As[4096];   // [128 rows][32 k], kg swizzled
    __shared__ __align__(16) short Bg[2048];   // [64 n][32 k]
    __shared__ __align__(16) short Bu[2048];
    __shared__ int toks[128];

    const int tid = threadIdx.x;
    if (tid < 128) toks[tid] = rows_tok[row0 + tid];
    __syncthreads();

    const int wave = tid >> 6, lane = tid & 63;
    const int lm = lane & 15, lq = lane >> 4;
    const int wm = wave >> 1, wn = wave & 1;

    // staging: s = tid (+256), row = s>>2, kgS = s&3, src kg = kgS ^ ((row>>1)&3)
    const int rA0 = tid >> 2, rA1 = 64 + (tid >> 2);
    const short* aSrc0 = xbf + (long)toks[rA0] * HD + (((tid & 3) ^ ((rA0 >> 1) & 3)) << 3);
    const short* aSrc1 = xbf + (long)toks[rA1] * HD + (((tid & 3) ^ ((rA1 >> 1) & 3)) << 3);
    const int nB = tid >> 2;
    const long wb = (long)e * NI2 * HD;
    const int kgB = ((tid & 3) ^ ((nB >> 1) & 3)) << 3;
    const short* gSrc = w1T + wb + (long)(i0 + nB) * HD + kgB;
    const short* uSrc = w1T + wb + (long)(NI + i0 + nB) * HD + kgB;

    short* aDst0 = As + wave * 512;
    short* aDst1 = As + 2048 + wave * 512;
    short* gDst = Bg + wave * 512;
    short* uDst = Bu + wave * 512;

    int aOff[4], bOff[2];
#pragma unroll
    for (int i = 0; i < 4; i++) {
        int r = wm * 64 + i * 16 + lm;
        aOff[i] = r * 32 + ((lq ^ ((r >> 1) & 3)) << 3);
    }
#pragma unroll
    for (int nf = 0; nf < 2; nf++) {
        int n = wn * 32 + nf * 16 + lm;
        bOff[nf] = n * 32 + ((lq ^ ((n >> 1) & 3)) << 3);
    }

    const f32x4 zero = {0.f, 0.f, 0.f, 0.f};
    f32x4 acc[4][4];
#pragma unroll
    for (int i = 0; i < 4; i++)
#pragma unroll
        for (int j = 0; j < 4; j++) acc[i][j] = zero;

    for (int kk = 0; kk < HD; kk += 32) {
        gload16(aSrc0 + kk, aDst0);
        gload16(aSrc1 + kk, aDst1);
        gload16(gSrc + kk, gDst);
        gload16(uSrc + kk, uDst);
        __syncthreads();
        short8 aF[4], gF[2], uF[2];
#pragma unroll
        for (int i = 0; i < 4; i++) aF[i] = *(const short8*)(As + aOff[i]);
#pragma unroll
        for (int nf = 0; nf < 2; nf++) {
            gF[nf] = *(const short8*)(Bg + bOff[nf]);
            uF[nf] = *(const short8*)(Bu + bOff[nf]);
        }
#pragma unroll
        for (int i = 0; i < 4; i++)
#pragma unroll
            for (int nf = 0; nf < 2; nf++) {
                acc[i][nf]     = __builtin_amdgcn_mfma_f32_16x16x32_bf16(aF[i], gF[nf], acc[i][nf], 0, 0, 0);
                acc[i][nf + 2] = __builtin_amdgcn_mfma_f32_16x16x32_bf16(aF[i], uF[nf], acc[i][nf + 2], 0, 0, 0);
            }
        __syncthreads();
    }

    const int arow0 = row0 - r0base + wm * 64 + lq * 4;
#pragma unroll
    for (int i = 0; i < 4; i++) {
#pragma unroll
        for (int nf = 0; nf < 2; nf++) {
            int col = i0 + wn * 32 + nf * 16 + lm;
#pragma unroll
            for (int r = 0; r < 4; r++) {
                float g = acc[i][nf][r], u = acc[i][nf + 2][r];
                float a = (g / (1.f + __expf(-g))) * u;
                act[(long)(arow0 + i * 16 + r) * NI + col] = f2bf(a);
            }
        }
    }
}

// ---------- 5. GEMM2: out += w * (act @ W2), full K, scaled atomics ----------
__global__ __launch_bounds__(256) void gemm2_kernel(
    const short* __restrict__ act, const short* __restrict__ w2T,
    const int* __restrict__ rows_tok, const float* __restrict__ rows_w,
    const int* __restrict__ ctrl, float* __restrict__ accum, float* __restrict__ doutf,
    int r0base)
{
    const int row0 = r0base + blockIdx.y * 128;
    if (row0 >= ctrl[24]) return;
    int e = 0;
#pragma unroll
    for (int q = 1; q < NEXP; q++) if (row0 >= ctrl[16 + q]) e = q;
    const int n0 = blockIdx.x * 128;

    __shared__ __align__(16) short As[4096];   // [128 rows][32 k]
    __shared__ __align__(16) short Bs[4096];   // [128 n][32 k]
    __shared__ int toks[128];
    __shared__ float rws[128];

    const int tid = threadIdx.x;
    if (tid < 128) { toks[tid] = rows_tok[row0 + tid]; rws[tid] = rows_w[row0 + tid]; }
    __syncthreads();

    const int wave = tid >> 6, lane = tid & 63;
    const int lm = lane & 15, lq = lane >> 4;
    const int wm = wave >> 1, wn = wave & 1;

    const int rA0 = tid >> 2, rA1 = 64 + (tid >> 2);
    const int arow = row0 - r0base;
    const short* aSrc0 = act + (long)(arow + rA0) * NI + (((tid & 3) ^ ((rA0 >> 1) & 3)) << 3);
    const short* aSrc1 = act + (long)(arow + rA1) * NI + (((tid & 3) ^ ((rA1 >> 1) & 3)) << 3);
    const long wb = (long)e * HD * NI;
    const short* bSrc0 = w2T + wb + (long)(n0 + rA0) * NI + (((tid & 3) ^ ((rA0 >> 1) & 3)) << 3);
    const short* bSrc1 = w2T + wb + (long)(n0 + rA1) * NI + (((tid & 3) ^ ((rA1 >> 1) & 3)) << 3);

    short* aDst0 = As + wave * 512;
    short* aDst1 = As + 2048 + wave * 512;
    short* bDst0 = Bs + wave * 512;
    short* bDst1 = Bs + 2048 + wave * 512;

    int aOff[4], bOff[4];
#pragma unroll
    for (int i = 0; i < 4; i++) {
        int r = wm * 64 + i * 16 + lm;
        aOff[i] = r * 32 + ((lq ^ ((r >> 1) & 3)) << 3);
        int n = wn * 64 + i * 16 + lm;
        bOff[i] = n * 32 + ((lq ^ ((n >> 1) & 3)) << 3);
    }

    const f32x4 zero = {0.f, 0.f, 0.f, 0.f};
    f32x4 acc[4][4];
#pragma unroll
    for (int i = 0; i < 4; i++)
#pragma unroll
        for (int j = 0; j < 4; j++) acc[i][j] = zero;

    for (int kk = 0; kk < NI; kk += 32) {
        gload16(aSrc0 + kk, aDst0);
        gload16(aSrc1 + kk, aDst1);
        gload16(bSrc0 + kk, bDst0);
        gload16(bSrc1 + kk, bDst1);
        __syncthreads();
        short8 aF[4], bF[4];
#pragma unroll
        for (int i = 0; i < 4; i++) {
            aF[i] = *(const short8*)(As + aOff[i]);
            bF[i] = *(const short8*)(Bs + bOff[i]);
        }
#pragma unroll
        for (int i = 0; i < 4; i++)
#pragma unroll
            for (int j = 0; j < 4; j++)
                acc[i][j] = __builtin_amdgcn_mfma_f32_16x16x32_bf16(aF[i], bF[j], acc[i][j], 0, 0, 0);
        __syncthreads();
    }

    const int flag = ctrl[31];
    float* dst = flag ? doutf : accum;
#pragma unroll
    for (int i = 0; i < 4; i++) {
        int rl = wm * 64 + i * 16 + lq * 4;
#pragma unroll
        for (int r = 0; r < 4; r++) {
            float w = rws[rl + r];
            if (w != 0.f) {
                long tb = (long)toks[rl + r] * HD + n0 + wn * 64 + lm;
#pragma unroll
                for (int j = 0; j < 4; j++)
                    atomicAdd(&dst[tb + j * 16], acc[i][j][r] * w);
            }
        }
    }
}

// ---------- 6. fp32 accum -> bf16 out (bf16 mode only) ----------
__global__ __launch_bounds__(256) void convert_kernel(
    const float* __restrict__ accum, short* __restrict__ out, const int* __restrict__ ctrl)
{
    if (ctrl[31]) return;   // fp32 mode: gemm2 wrote d_out directly
    int i = blockIdx.x * 256 + threadIdx.x;
    out[i] = f2bf(accum[i]);
}

extern "C" void kernel_launch(void* const* d_in, const int* in_sizes, int n_in,
                              void* d_out, int out_size, void* d_ws, size_t ws_size,
                              hipStream_t stream) {
    char* ws = (char*)d_ws;
    // layout: ctrl | top_i | top_w | rows_tok | rows_w | x_bf | w1T | w2T | accum | act(row-chunk)
    int*   ctrl     = (int*)ws;
    int*   top_i    = (int*)(ws + 512);
    float* top_w    = (float*)(ws + 66048);
    int*   rows_tok = (int*)(ws + 131584);
    float* rows_w   = (float*)(ws + 201216);
    short* xbf      = (short*)(ws + 270848);
    short* w1T      = (short*)(ws + 17048064);    // 92,274,688 B
    short* w2T      = (short*)(ws + 109322752);   // 46,137,344 B
    float* accum    = (float*)(ws + 155460096);   // 33,554,432 B
    short* act      = (short*)(ws + 189014528);   // RC * NI * 2 B

    const long act_off = 189014528L;
    long RC = ((long)ws_size - act_off) / (NI * 2);
    RC &= ~127L;
    if (RC > MAXROWS) RC = MAXROWS;
    if (RC < 128) RC = 128;
    // hard clamp: never let act extend past the workspace
    while (RC > 128 && act_off + RC * (NI * 2) > (long)ws_size) RC -= 128;

    hipMemsetAsync(ws, 0, 512, stream);                       // ctrl
    hipMemsetAsync(ws + 155460096, 0, 33554432, stream);      // accum
    hipMemsetAsync(d_out, 0, (size_t)out_size * 2, stream);   // safe for both dtypes

    detect_kernel<<<1, 256, 0, stream>>>((const unsigned short*)d_in[0], ctrl);
    cvt_x_kernel<<<TOK * HD / 256, 256, 0, stream>>>(d_in[0], xbf, ctrl);
    transpose_w_kernel<<<dim3(NI2 / 64, HD / 64, NEXP), 256, 0, stream>>>(d_in[2], w1T, ctrl, HD, NI2);
    transpose_w_kernel<<<dim3(HD / 64, NI / 64, NEXP), 256, 0, stream>>>(d_in[3], w2T, ctrl, NI, HD);
    gate_kernel<<<TOK / 4, 256, 0, stream>>>(d_in[0], d_in[1], top_i, top_w, ctrl);
    offsets_pad_kernel<<<1, 256, 0, stream>>>(ctrl, rows_tok, rows_w);
    scatter_kernel<<<TOK / 256, 256, 0, stream>>>(top_i, top_w, ctrl, rows_tok, rows_w);

    for (long r0 = 0; r0 < MAXROWS; r0 += RC) {
        long rc = MAXROWS - r0; if (rc > RC) rc = RC;
        gemm1_kernel<<<dim3(NI / 64, rc / 128), 256, 0, stream>>>(
            xbf, w1T, rows_tok, ctrl, act, (int)r0);
        gemm2_kernel<<<dim3(HD / 128, rc / 128), 256, 0, stream>>>(
            act, w2T, rows_tok, rows_w, ctrl, accum, (float*)d_out, (int)r0);
    }
    convert_kernel<<<TOK * HD / 256, 256, 0, stream>>>(accum, (short*)d_out, ctrl);
}